// Round 18
// baseline (302.021 us; speedup 1.0000x reference)
//
#include <hip/hip_runtime.h>

#define S_LEN 2048
#define DM 2048
#define NH 16
#define DK 128
#define BB 2
#define BH (BB*NH)
#define GK 2048

typedef float f32x4 __attribute__((ext_vector_type(4)));
typedef __bf16 bf16x8 __attribute__((ext_vector_type(8)));
typedef __bf16 bf16x4 __attribute__((ext_vector_type(4)));
typedef unsigned int u32;

#define AS1 __attribute__((address_space(1)))
#define AS3 __attribute__((address_space(3)))

__device__ inline void gload16(const void* g, void* l){
  __builtin_amdgcn_global_load_lds((AS1 const u32*)g, (AS3 u32*)l, 16, 0, 0);
}

__device__ inline ushort f2bf(float f){
  __bf16 h = (__bf16)f;
  ushort u;
  __builtin_memcpy(&u, &h, 2);
  return u;
}

// ---------------- all fp32->bf16 conversions + rope table in one launch ----------------
__global__ void k_conv(const float* __restrict__ x, const float* __restrict__ wq,
                       const float* __restrict__ wk, const float* __restrict__ wv,
                       const float* __restrict__ wo4,
                       ushort* __restrict__ xb, ushort* __restrict__ dqkv,
                       ushort* __restrict__ dwo,
                       const int* __restrict__ pos, float2* __restrict__ cs){
  int bid = blockIdx.x;
  if (bid >= 24576){
    int idx = (bid - 24576) * 256 + threadIdx.x;   // < 131072 = S*64
    int s = idx >> 6, i = idx & 63;
    float inv = expf(-0.14391156831212787f * (float)i);   // 10000^(-i/64)
    float f = (float)pos[s] * inv;
    cs[idx] = make_float2(cosf(f), sinf(f));
    return;
  }
  int i = bid * 256 + threadIdx.x;    // 0 .. 6M-1 (float4 units)
  int sel = i >> 20;
  int off = i & ((1 << 20) - 1);
  const float* s; ushort* d;
  if (sel < 2){ s = x + ((size_t)sel << 22); d = xb + ((size_t)sel << 22); }
  else if (sel == 2){ s = wq; d = dqkv; }
  else if (sel == 3){ s = wk; d = dqkv + (size_t)DM * DM; }
  else if (sel == 4){ s = wv; d = dqkv + (size_t)2 * DM * DM; }
  else { s = wo4; d = dwo; }
  float4 v = reinterpret_cast<const float4*>(s)[off];
  ushort4 o;
  o.x = f2bf(v.x); o.y = f2bf(v.y); o.z = f2bf(v.z); o.w = f2bf(v.w);
  reinterpret_cast<ushort4*>(d)[off] = o;
}

#define SBAR() do{ __builtin_amdgcn_s_barrier(); __builtin_amdgcn_sched_barrier(0); }while(0)
#define VMC(n) asm volatile("s_waitcnt vmcnt(" #n ")" ::: "memory")

// ================= Q+K GEMM: 256x256 tile, BK=64, 8 waves, 8-phase =================
#define STG(slot, srcp, tks, khh) do{ \
  const ushort* _s = (srcp) + (tks)*64 + (khh)*32; \
  gload16(_s,                    lds + (slot)*8192 + wid*512); \
  gload16(_s + (size_t)128*GK,   lds + (slot)*8192 + 4096 + wid*512); \
}while(0)

#define RD_A(slot, mh) do{ \
  af[0] = *reinterpret_cast<const bf16x8*>(ldsc + (slot)*16384 + wm*8192 + ((mh)*4+0)*1024 + frA); \
  af[1] = *reinterpret_cast<const bf16x8*>(ldsc + (slot)*16384 + wm*8192 + ((mh)*4+1)*1024 + frA); \
  af[2] = *reinterpret_cast<const bf16x8*>(ldsc + (slot)*16384 + wm*8192 + ((mh)*4+2)*1024 + frA); \
  af[3] = *reinterpret_cast<const bf16x8*>(ldsc + (slot)*16384 + wm*8192 + ((mh)*4+3)*1024 + frA); \
}while(0)

#define RD_B(slot) do{ \
  bfr[0] = *reinterpret_cast<const bf16x8*>(ldsc + (slot)*16384 + wn*4096 + 0*1024 + frA); \
  bfr[1] = *reinterpret_cast<const bf16x8*>(ldsc + (slot)*16384 + wn*4096 + 1*1024 + frA); \
  bfr[2] = *reinterpret_cast<const bf16x8*>(ldsc + (slot)*16384 + wn*4096 + 2*1024 + frA); \
  bfr[3] = *reinterpret_cast<const bf16x8*>(ldsc + (slot)*16384 + wn*4096 + 3*1024 + frA); \
}while(0)

#define MM(mh) do{ \
  __builtin_amdgcn_s_setprio(1); \
  _Pragma("unroll") \
  for (int mf2 = 0; mf2 < 4; mf2++) \
    _Pragma("unroll") \
    for (int nf = 0; nf < 4; nf++) \
      acc[(mh)*4+mf2][nf] = __builtin_amdgcn_mfma_f32_16x16x32_bf16(af[mf2], bfr[nf], acc[(mh)*4+mf2][nf], 0, 0, 0); \
  __builtin_amdgcn_s_setprio(0); \
}while(0)

__launch_bounds__(512, 2)
__global__ void k_gemm_qk(const ushort* __restrict__ A, const ushort* __restrict__ Bt,
                          const float2* __restrict__ cs,
                          ushort* __restrict__ Qh, ushort* __restrict__ Kh){
  __shared__ short lds[65536];   // 128 KiB: 8 half-slots x 16 KB
  const int tid = threadIdx.x, lane = tid & 63, wid = tid >> 6;
  const int wm = wid >> 2, wn = wid & 3;
  const int fr = lane & 15, fq = lane >> 4;

  const int bid = blockIdx.x;                  // 256 = 8*32, bijective XCD swizzle
  const int b2 = (bid & 7) * 32 + (bid >> 3);
  const int by = b2 >> 4, bx = b2 & 15;

  const int rbase = wid * 16 + (lane >> 2);
  const int kup = ((lane & 3) ^ ((lane >> 3) & 3)) * 8;
  const ushort* pa = A  + (size_t)(by * 256 + rbase) * GK + kup;
  const ushort* pb = Bt + (size_t)(bx * 256 + rbase) * GK + kup;

  const char* ldsc = (const char*)lds;
  const int frA = fr * 64 + ((fq * 16) ^ (((fr >> 1) & 3) << 4));

  f32x4 acc[8][4] = {};
  bf16x8 af[4], bfr[4];

  STG(0, pa, 0, 0); STG(1, pb, 0, 0); STG(2, pa, 0, 1); STG(3, pb, 0, 1);
  STG(4, pa, 1, 0); STG(5, pb, 1, 0);
  VMC(8);
  SBAR();

  #pragma unroll 1
  for (int it = 0; it < 16; ++it){
    const int tb  = 2 * it + 1;
    const int tn  = (2 * it + 2 < 32) ? 2 * it + 2 : 31;
    const int tn1 = (2 * it + 3 < 32) ? 2 * it + 3 : 31;
    RD_A(0, 0); RD_B(1); STG(6, pa, tb, 1);           SBAR(); MM(0); SBAR();
    RD_A(0, 1);          STG(7, pb, tb, 1);  VMC(6);  SBAR(); MM(1); SBAR();
    RD_A(2, 0); RD_B(3); STG(0, pa, tn, 0);           SBAR(); MM(0); SBAR();
    RD_A(2, 1);          STG(1, pb, tn, 0);  VMC(6);  SBAR(); MM(1); SBAR();
    RD_A(4, 0); RD_B(5); STG(2, pa, tn, 1);           SBAR(); MM(0); SBAR();
    RD_A(4, 1);          STG(3, pb, tn, 1);  VMC(6);  SBAR(); MM(1); SBAR();
    RD_A(6, 0); RD_B(7); STG(4, pa, tn1, 0);          SBAR(); MM(0); SBAR();
    RD_A(6, 1);          STG(5, pb, tn1, 0); VMC(6);  SBAR(); MM(1); SBAR();
  }

  const int rowb = by * 256 + wm * 128 + fq * 4;
  const bool isQ = (bx < 8);
  ushort* dst = isQ ? Qh : Kh;
  const float qscl = isQ ? 0.08838834764831845f : 1.0f;
  #pragma unroll
  for (int mf = 0; mf < 8; mf++)
    #pragma unroll
    for (int nf = 0; nf < 4; nf++){
      int col = bx * 256 + wn * 64 + nf * 16 + fr;
      int cg = col & 2047;
      int hh = cg >> 7, dd = cg & 127, jj = (cg >> 1) & 63;
      #pragma unroll
      for (int i = 0; i < 4; i++){
        int row = rowb + mf * 16 + i;
        int s = row & (S_LEN - 1), bb = row >> 11;
        float2 c2 = cs[s * 64 + jj];
        float v = acc[mf][nf][i];
        float p = __shfl_xor(v, 1);
        float o = (fr & 1) ? fmaf(p, c2.y, v * c2.x) : fmaf(v, c2.x, -p * c2.y);
        dst[((size_t)(bb * NH + hh) * S_LEN + s) * DK + dd] = f2bf(o * qscl);
      }
    }
}

// ================= 256x128 8-phase skeleton (shared by V GEMM and WO GEMM) =================
#define WSTG_A(si, tks, khh) do{ \
  const ushort* _s = pa + (tks)*64 + (khh)*32; \
  gload16(_s,                  lds + (si)*8192 + wid*512); \
  gload16(_s + (size_t)128*GK, lds + (si)*8192 + 4096 + wid*512); \
}while(0)
#define WSTG_B(si, tks, khh) do{ \
  const ushort* _s = pb + (tks)*64 + (khh)*32; \
  gload16(_s, lds + 32768 + (si)*4096 + wid*512); \
}while(0)
#define WRD_A(si, mhf) do{ \
  af[0] = *reinterpret_cast<const bf16x8*>(ldsc + (si)*16384 + wm*4096 + ((mhf)*2+0)*1024 + frA); \
  af[1] = *reinterpret_cast<const bf16x8*>(ldsc + (si)*16384 + wm*4096 + ((mhf)*2+1)*1024 + frA); \
}while(0)
#define WRD_B(si) do{ \
  bfr[0] = *reinterpret_cast<const bf16x8*>(ldsc + 65536 + (si)*8192 + wn*4096 + 0*1024 + frA); \
  bfr[1] = *reinterpret_cast<const bf16x8*>(ldsc + 65536 + (si)*8192 + wn*4096 + 1*1024 + frA); \
  bfr[2] = *reinterpret_cast<const bf16x8*>(ldsc + 65536 + (si)*8192 + wn*4096 + 2*1024 + frA); \
  bfr[3] = *reinterpret_cast<const bf16x8*>(ldsc + 65536 + (si)*8192 + wn*4096 + 3*1024 + frA); \
}while(0)
#define WMM(mhf) do{ \
  __builtin_amdgcn_s_setprio(1); \
  _Pragma("unroll") \
  for (int k2 = 0; k2 < 2; k2++) \
    _Pragma("unroll") \
    for (int nf = 0; nf < 4; nf++) \
      acc[(mhf)*2+k2][nf] = __builtin_amdgcn_mfma_f32_16x16x32_bf16(af[k2], bfr[nf], acc[(mhf)*2+k2][nf], 0, 0, 0); \
  __builtin_amdgcn_s_setprio(0); \
}while(0)

#define WBODY() \
  WSTG_A(0, 0, 0); WSTG_B(0, 0, 0); WSTG_A(1, 0, 1); WSTG_B(1, 0, 1); \
  WSTG_A(2, 1, 0); WSTG_B(2, 1, 0); \
  VMC(6); \
  SBAR(); \
  _Pragma("unroll 1") \
  for (int it = 0; it < 16; ++it){ \
    const int tb  = 2 * it + 1; \
    const int tn  = (2 * it + 2 < 32) ? 2 * it + 2 : 31; \
    const int tn1 = (2 * it + 3 < 32) ? 2 * it + 3 : 31; \
    WRD_A(0, 0); WRD_B(0); WSTG_A(3, tb, 1);            SBAR(); WMM(0); SBAR(); \
    WRD_A(0, 1);           WSTG_B(3, tb, 1);  VMC(6);   SBAR(); WMM(1); SBAR(); \
    WRD_A(1, 0); WRD_B(1); WSTG_A(0, tn, 0);            SBAR(); WMM(0); SBAR(); \
    WRD_A(1, 1);           WSTG_B(0, tn, 0);  VMC(6);   SBAR(); WMM(1); SBAR(); \
    WRD_A(2, 0); WRD_B(2); WSTG_A(1, tn, 1);            SBAR(); WMM(0); SBAR(); \
    WRD_A(2, 1);           WSTG_B(1, tn, 1);  VMC(6);   SBAR(); WMM(1); SBAR(); \
    WRD_A(3, 0); WRD_B(3); WSTG_A(2, tn1, 0);           SBAR(); WMM(0); SBAR(); \
    WRD_A(3, 1);           WSTG_B(2, tn1, 0); VMC(6);   SBAR(); WMM(1); SBAR(); \
  }

__launch_bounds__(512, 2)
__global__ void k_gemm_v(const ushort* __restrict__ A, const ushort* __restrict__ Bt,
                         ushort* __restrict__ Vt){
  __shared__ short lds[49152];   // 96 KiB
  const int tid = threadIdx.x, lane = tid & 63, wid = tid >> 6;
  const int wm = wid >> 1, wn = wid & 1;
  const int fr = lane & 15, fq = lane >> 4;

  const int bid = blockIdx.x;
  const int b2 = (bid & 7) * 32 + (bid >> 3);
  const int by = b2 >> 4, bx = b2 & 15;

  const int rbase = wid * 16 + (lane >> 2);
  const int kup = ((lane & 3) ^ ((lane >> 3) & 3)) * 8;
  const ushort* pa = A  + (size_t)(by * 256 + rbase) * GK + kup;
  const ushort* pb = Bt + (size_t)(bx * 128 + rbase) * GK + kup;

  const char* ldsc = (const char*)lds;
  const int frA = fr * 64 + ((fq * 16) ^ (((fr >> 1) & 3) << 4));

  f32x4 acc[4][4] = {};
  bf16x8 af[2], bfr[4];

  WBODY();

  const int rowb = by * 256 + wm * 64 + fq * 4;
  #pragma unroll
  for (int mf = 0; mf < 4; mf++){
    int row0 = rowb + mf * 16;
    int s0 = row0 & (S_LEN - 1), bb = row0 >> 11;
    #pragma unroll
    for (int nf = 0; nf < 4; nf++){
      int col = bx * 128 + wn * 64 + nf * 16 + fr;
      int hh = col >> 7, dd = col & 127;
      ushort4 o;
      o.x = f2bf(acc[mf][nf][0]); o.y = f2bf(acc[mf][nf][1]);
      o.z = f2bf(acc[mf][nf][2]); o.w = f2bf(acc[mf][nf][3]);
      *reinterpret_cast<ushort4*>(&Vt[((size_t)(bb * NH + hh) * DK + dd) * S_LEN + s0]) = o;
    }
  }
}

__launch_bounds__(512, 2)
__global__ void k_gemm_wo(const ushort* __restrict__ A, const ushort* __restrict__ Bt,
                          float* __restrict__ C){
  __shared__ short lds[49152];   // 96 KiB
  const int tid = threadIdx.x, lane = tid & 63, wid = tid >> 6;
  const int wm = wid >> 1, wn = wid & 1;
  const int fr = lane & 15, fq = lane >> 4;

  const int bid = blockIdx.x;
  const int b2 = (bid & 7) * 32 + (bid >> 3);
  const int by = b2 >> 4, bx = b2 & 15;

  const int rbase = wid * 16 + (lane >> 2);
  const int kup = ((lane & 3) ^ ((lane >> 3) & 3)) * 8;
  const ushort* pa = A  + (size_t)(by * 256 + rbase) * GK + kup;
  const ushort* pb = Bt + (size_t)(bx * 128 + rbase) * GK + kup;

  const char* ldsc = (const char*)lds;
  const int frA = fr * 64 + ((fq * 16) ^ (((fr >> 1) & 3) << 4));

  f32x4 acc[4][4] = {};
  bf16x8 af[2], bfr[4];

  WBODY();

  const int orow = by * 256 + wm * 64 + fq * 4;
  const int ocol = bx * 128 + wn * 64 + fr;
  #pragma unroll
  for (int mf = 0; mf < 4; mf++)
    #pragma unroll
    for (int nf = 0; nf < 4; nf++)
      #pragma unroll
      for (int i = 0; i < 4; i++)
        C[(size_t)(orow + mf * 16 + i) * DM + ocol + nf * 16] = acc[mf][nf][i];
}

// ---------------- causal flash attention: K direct from L2, V in LDS ----------------
// r16/r17 grid (512 blocks x 4 waves x 16 q-rows, paired 64-row chunks, 33 tiles uniform,
// 2 blocks/CU = 8 waves/CU). K fragments are wave-invariant -> read DIRECT from global
// (L2-resident: all blocks of a bh share one XCD, bid%8==bh%8). Removes K staging + 64
// K LDS reads per tile-block (-45% LDS traffic). All 16 K loads hoisted before the MFMA
// cluster (independent; ~200cyc L2 latency hidden by 8-wave TLP). T5 setprio on MFMA.
__launch_bounds__(256, 2)
__global__ void k_attn(const ushort* __restrict__ Q, const ushort* __restrict__ K,
                       const ushort* __restrict__ Vt, ushort* __restrict__ O){
  __shared__ short Vl[2][128 * 64];   // [d][kv] swizzled (16KB each)
  __shared__ short Pl[4][16 * 80];    // per-wave P, 160B row stride (2.5KB each)
  const int tid = threadIdx.x, lane = tid & 63, wid = tid >> 6;
  const int bid = blockIdx.x;
  const int pid = bid >> 5;           // 0..15
  const int bh = bid & 31;
  const int b = bh >> 4, h = bh & 15;
  const int fr = lane & 15, fq = lane >> 4;
  const int vswz = (fr & 7) << 4;

  const ushort* kb = K  + (size_t)bh * S_LEN * DK;
  const ushort* vb = Vt + (size_t)bh * DK * S_LEN;
  char* PlB = (char*)Pl + wid * 2560;
  ushort* ob = O + (size_t)b * S_LEN * DM;

  // V staging: 4 waves x 4 instrs (16KB tile)
  int vro[4], vco[4];
  #pragma unroll
  for (int jj = 0; jj < 4; jj++){
    int ins = wid * 4 + jj;
    vro[jj] = ins * 8 + (lane >> 3);
    vco[jj] = 8 * ((lane & 7) ^ (vro[jj] & 7));
  }

  #pragma unroll 1
  for (int half = 0; half < 2; half++){
    const int j = half ? pid : 31 - pid;      // 64-row chunk index, 0..31
    const int qr = j * 64 + wid * 16;
    const int nt = j + 1;                     // kv tiles of 64

    bf16x8 qf[4];
    #pragma unroll
    for (int c = 0; c < 4; c++)
      qf[c] = *reinterpret_cast<const bf16x8*>(
          Q + ((size_t)bh * S_LEN + qr + fr) * DK + c * 32 + fq * 8);

    float mi = -1e30f, li = 0.f;     // per-lane scalars: q-row = qr + fr
    f32x4 accO[8] = {};

    __syncthreads();                  // protect buffers from previous half's readers
    #pragma unroll
    for (int jj = 0; jj < 4; jj++){
      int ins = wid * 4 + jj;
      gload16(vb + (size_t)vro[jj] * S_LEN + vco[jj], (char*)Vl + ins * 1024);
    }
    __syncthreads();

    #pragma unroll 1
    for (int kt = 0; kt < nt; kt++){
      const int k0 = kt * 64;
      const int cur = kt & 1;
      if (kt + 1 < nt){
        const int k1 = k0 + 64;
        char* vd = (char*)Vl + (cur ^ 1) * 16384;
        #pragma unroll
        for (int jj = 0; jj < 4; jj++){
          int ins = wid * 4 + jj;
          gload16(vb + (size_t)vro[jj] * S_LEN + k1 + vco[jj], vd + ins * 1024);
        }
      }
      const char* VlB = (const char*)Vl + cur * 16384;

      // ---- K fragments direct from global (L2-hot), all 16 issued up-front ----
      bf16x8 kf[4][4];
      #pragma unroll
      for (int c = 0; c < 4; c++)
        #pragma unroll
        for (int ch = 0; ch < 4; ch++)
          kf[c][ch] = *reinterpret_cast<const bf16x8*>(
              kb + (size_t)(k0 + ch * 16 + fr) * DK + c * 32 + fq * 8);

      // ---- swapped QK^T (Q pre-scaled): lane owns q=fr, kv=16ch+4fq+i ----
      f32x4 sc[4] = {};
      __builtin_amdgcn_s_setprio(1);
      #pragma unroll
      for (int c = 0; c < 4; c++)
        #pragma unroll
        for (int ch = 0; ch < 4; ch++)
          sc[ch] = __builtin_amdgcn_mfma_f32_16x16x32_bf16(kf[c][ch], qf[c], sc[ch], 0, 0, 0);
      __builtin_amdgcn_s_setprio(0);

      // ---- causal mask on last tile (kv = k0+16ch+4fq+i vs q = qr+fr) ----
      const int qrow = qr + fr;
      if (kt == nt - 1){
        #pragma unroll
        for (int ch = 0; ch < 4; ch++)
          #pragma unroll
          for (int i = 0; i < 4; i++)
            if (k0 + ch * 16 + fq * 4 + i > qrow) sc[ch][i] = -1e30f;
      }

      // ---- in-register row max + 2 shfl ----
      float mx = sc[0][0];
      #pragma unroll
      for (int ch = 0; ch < 4; ch++)
        #pragma unroll
        for (int i = 0; i < 4; i++) mx = fmaxf(mx, sc[ch][i]);
      mx = fmaxf(mx, __shfl_xor(mx, 16));
      mx = fmaxf(mx, __shfl_xor(mx, 32));

      // ---- T13 defer-max ----
      if (!__all(mx <= mi + 8.0f)){
        float mn = fmaxf(mi, mx);
        float scl = __expf(mi - mn);
        mi = mn;
        li *= scl;
        float sclq[4];
        #pragma unroll
        for (int i = 0; i < 4; i++) sclq[i] = __shfl(scl, fq * 4 + i);
        #pragma unroll
        for (int dt = 0; dt < 8; dt++)
          #pragma unroll
          for (int i = 0; i < 4; i++) accO[dt][i] *= sclq[i];
      }

      float rs = 0.f;
      #pragma unroll
      for (int ch = 0; ch < 4; ch++)
        #pragma unroll
        for (int i = 0; i < 4; i++){
          float e = __expf(sc[ch][i] - mi);
          sc[ch][i] = e;
          rs += e;
        }
      rs += __shfl_xor(rs, 16);
      rs += __shfl_xor(rs, 32);
      li += rs;

      // ---- P -> LDS: native casts (cvt_pk) packed to one b64 per ch ----
      #pragma unroll
      for (int ch = 0; ch < 4; ch++){
        bf16x4 pk;
        pk[0] = (__bf16)sc[ch][0]; pk[1] = (__bf16)sc[ch][1];
        pk[2] = (__bf16)sc[ch][2]; pk[3] = (__bf16)sc[ch][3];
        *reinterpret_cast<bf16x4*>(PlB + fr * 160 + ch * 32 + fq * 8) = pk;
      }
      bf16x8 pf[2];
      #pragma unroll
      for (int c2 = 0; c2 < 2; c2++)
        pf[c2] = *reinterpret_cast<const bf16x8*>(PlB + fr * 160 + c2 * 64 + fq * 16);

      // ---- PV ----
      __builtin_amdgcn_s_setprio(1);
      #pragma unroll
      for (int dt = 0; dt < 8; dt++)
        #pragma unroll
        for (int c2 = 0; c2 < 2; c2++){
          bf16x8 vf = *reinterpret_cast<const bf16x8*>(
              VlB + (dt * 16 + fr) * 128 + ((c2 * 64 + fq * 16) ^ vswz));
          accO[dt] = __builtin_amdgcn_mfma_f32_16x16x32_bf16(pf[c2], vf, accO[dt], 0, 0, 0);
        }
      __builtin_amdgcn_s_setprio(0);
      __syncthreads();
    }

    // ---- epilogue: inv in accO layout ----
    float inv[4];
    #pragma unroll
    for (int i = 0; i < 4; i++) inv[i] = 1.f / __shfl(li, fq * 4 + i);
    #pragma unroll
    for (int dt = 0; dt < 8; dt++)
      #pragma unroll
      for (int i = 0; i < 4; i++){
        int row = qr + fq * 4 + i;
        ob[(size_t)row * DM + h * DK + dt * 16 + fr] = f2bf(accO[dt][i] * inv[i]);
      }
  }
}

extern "C" void kernel_launch(void* const* d_in, const int* in_sizes, int n_in,
                              void* d_out, int out_size, void* d_ws, size_t ws_size,
                              hipStream_t stream){
  const float* x  = (const float*)d_in[0];
  const float* wq = (const float*)d_in[1];
  const float* wk = (const float*)d_in[2];
  const float* wv = (const float*)d_in[3];
  const float* wo = (const float*)d_in[4];
  const int* pos  = (const int*)d_in[5];
  float* out = (float*)d_out;

  char* ws = (char*)d_ws;
  ushort* xb   = (ushort*)(ws);               // 16 MiB; Ob aliases after GEMMs consume xb
  ushort* Ob   = xb;
  ushort* wqkv = (ushort*)(ws + 16777216);    // 24 MiB
  ushort* Qh   = (ushort*)(ws + 41943040);    // 16 MiB
  ushort* Kh   = (ushort*)(ws + 58720256);    // 16 MiB
  ushort* Vt   = (ushort*)(ws + 75497472);    // 16 MiB
  float2* cs   = (float2*)(ws + 92274688);    // 1 MiB
  ushort* wob  = (ushort*)(ws + 93323264);    // 8 MiB

  k_conv<<<24576 + 512, 256, 0, stream>>>(x, wq, wk, wv, wo, xb, wqkv, wob, pos, cs);

  k_gemm_qk<<<256, 512, 0, stream>>>(xb, wqkv, cs, Qh, Kh);
  k_gemm_v<<<256, 512, 0, stream>>>(xb, wqkv + (size_t)2 * DM * DM, Vt);

  k_attn<<<512, 256, 0, stream>>>(Qh, Kh, Vt, Ob);

  k_gemm_wo<<<256, 512, 0, stream>>>(Ob, wob, out);
}

// Round 19
// 237.455 us; speedup vs baseline: 1.2719x; 1.2719x over previous
//
#include <hip/hip_runtime.h>

#define S_LEN 2048
#define DM 2048
#define NH 16
#define DK 128
#define BB 2
#define BH (BB*NH)
#define GK 2048

typedef float f32x4 __attribute__((ext_vector_type(4)));
typedef __bf16 bf16x8 __attribute__((ext_vector_type(8)));
typedef __bf16 bf16x4 __attribute__((ext_vector_type(4)));
typedef unsigned int u32;

#define AS1 __attribute__((address_space(1)))
#define AS3 __attribute__((address_space(3)))

__device__ inline void gload16(const void* g, void* l){
  __builtin_amdgcn_global_load_lds((AS1 const u32*)g, (AS3 u32*)l, 16, 0, 0);
}

__device__ inline ushort f2bf(float f){
  __bf16 h = (__bf16)f;
  ushort u;
  __builtin_memcpy(&u, &h, 2);
  return u;
}

// ---------------- all fp32->bf16 conversions + rope table in one launch ----------------
__global__ void k_conv(const float* __restrict__ x, const float* __restrict__ wq,
                       const float* __restrict__ wk, const float* __restrict__ wv,
                       const float* __restrict__ wo4,
                       ushort* __restrict__ xb, ushort* __restrict__ dqkv,
                       ushort* __restrict__ dwo,
                       const int* __restrict__ pos, float2* __restrict__ cs){
  int bid = blockIdx.x;
  if (bid >= 24576){
    int idx = (bid - 24576) * 256 + threadIdx.x;   // < 131072 = S*64
    int s = idx >> 6, i = idx & 63;
    float inv = expf(-0.14391156831212787f * (float)i);   // 10000^(-i/64)
    float f = (float)pos[s] * inv;
    cs[idx] = make_float2(cosf(f), sinf(f));
    return;
  }
  int i = bid * 256 + threadIdx.x;    // 0 .. 6M-1 (float4 units)
  int sel = i >> 20;
  int off = i & ((1 << 20) - 1);
  const float* s; ushort* d;
  if (sel < 2){ s = x + ((size_t)sel << 22); d = xb + ((size_t)sel << 22); }
  else if (sel == 2){ s = wq; d = dqkv; }
  else if (sel == 3){ s = wk; d = dqkv + (size_t)DM * DM; }
  else if (sel == 4){ s = wv; d = dqkv + (size_t)2 * DM * DM; }
  else { s = wo4; d = dwo; }
  float4 v = reinterpret_cast<const float4*>(s)[off];
  ushort4 o;
  o.x = f2bf(v.x); o.y = f2bf(v.y); o.z = f2bf(v.z); o.w = f2bf(v.w);
  reinterpret_cast<ushort4*>(d)[off] = o;
}

#define SBAR() do{ __builtin_amdgcn_s_barrier(); __builtin_amdgcn_sched_barrier(0); }while(0)
#define VMC(n) asm volatile("s_waitcnt vmcnt(" #n ")" ::: "memory")

// ================= Q+K GEMM: 256x256 tile, BK=64, 8 waves, 8-phase =================
#define STG(slot, srcp, tks, khh) do{ \
  const ushort* _s = (srcp) + (tks)*64 + (khh)*32; \
  gload16(_s,                    lds + (slot)*8192 + wid*512); \
  gload16(_s + (size_t)128*GK,   lds + (slot)*8192 + 4096 + wid*512); \
}while(0)

#define RD_A(slot, mh) do{ \
  af[0] = *reinterpret_cast<const bf16x8*>(ldsc + (slot)*16384 + wm*8192 + ((mh)*4+0)*1024 + frA); \
  af[1] = *reinterpret_cast<const bf16x8*>(ldsc + (slot)*16384 + wm*8192 + ((mh)*4+1)*1024 + frA); \
  af[2] = *reinterpret_cast<const bf16x8*>(ldsc + (slot)*16384 + wm*8192 + ((mh)*4+2)*1024 + frA); \
  af[3] = *reinterpret_cast<const bf16x8*>(ldsc + (slot)*16384 + wm*8192 + ((mh)*4+3)*1024 + frA); \
}while(0)

#define RD_B(slot) do{ \
  bfr[0] = *reinterpret_cast<const bf16x8*>(ldsc + (slot)*16384 + wn*4096 + 0*1024 + frA); \
  bfr[1] = *reinterpret_cast<const bf16x8*>(ldsc + (slot)*16384 + wn*4096 + 1*1024 + frA); \
  bfr[2] = *reinterpret_cast<const bf16x8*>(ldsc + (slot)*16384 + wn*4096 + 2*1024 + frA); \
  bfr[3] = *reinterpret_cast<const bf16x8*>(ldsc + (slot)*16384 + wn*4096 + 3*1024 + frA); \
}while(0)

#define MM(mh) do{ \
  __builtin_amdgcn_s_setprio(1); \
  _Pragma("unroll") \
  for (int mf2 = 0; mf2 < 4; mf2++) \
    _Pragma("unroll") \
    for (int nf = 0; nf < 4; nf++) \
      acc[(mh)*4+mf2][nf] = __builtin_amdgcn_mfma_f32_16x16x32_bf16(af[mf2], bfr[nf], acc[(mh)*4+mf2][nf], 0, 0, 0); \
  __builtin_amdgcn_s_setprio(0); \
}while(0)

__launch_bounds__(512, 2)
__global__ void k_gemm_qk(const ushort* __restrict__ A, const ushort* __restrict__ Bt,
                          const float2* __restrict__ cs,
                          ushort* __restrict__ Qh, ushort* __restrict__ Kh){
  __shared__ short lds[65536];   // 128 KiB: 8 half-slots x 16 KB
  const int tid = threadIdx.x, lane = tid & 63, wid = tid >> 6;
  const int wm = wid >> 2, wn = wid & 3;
  const int fr = lane & 15, fq = lane >> 4;

  const int bid = blockIdx.x;                  // 256 = 8*32, bijective XCD swizzle
  const int b2 = (bid & 7) * 32 + (bid >> 3);
  const int by = b2 >> 4, bx = b2 & 15;

  const int rbase = wid * 16 + (lane >> 2);
  const int kup = ((lane & 3) ^ ((lane >> 3) & 3)) * 8;
  const ushort* pa = A  + (size_t)(by * 256 + rbase) * GK + kup;
  const ushort* pb = Bt + (size_t)(bx * 256 + rbase) * GK + kup;

  const char* ldsc = (const char*)lds;
  const int frA = fr * 64 + ((fq * 16) ^ (((fr >> 1) & 3) << 4));

  f32x4 acc[8][4] = {};
  bf16x8 af[4], bfr[4];

  STG(0, pa, 0, 0); STG(1, pb, 0, 0); STG(2, pa, 0, 1); STG(3, pb, 0, 1);
  STG(4, pa, 1, 0); STG(5, pb, 1, 0);
  VMC(8);
  SBAR();

  #pragma unroll 1
  for (int it = 0; it < 16; ++it){
    const int tb  = 2 * it + 1;
    const int tn  = (2 * it + 2 < 32) ? 2 * it + 2 : 31;
    const int tn1 = (2 * it + 3 < 32) ? 2 * it + 3 : 31;
    RD_A(0, 0); RD_B(1); STG(6, pa, tb, 1);           SBAR(); MM(0); SBAR();
    RD_A(0, 1);          STG(7, pb, tb, 1);  VMC(6);  SBAR(); MM(1); SBAR();
    RD_A(2, 0); RD_B(3); STG(0, pa, tn, 0);           SBAR(); MM(0); SBAR();
    RD_A(2, 1);          STG(1, pb, tn, 0);  VMC(6);  SBAR(); MM(1); SBAR();
    RD_A(4, 0); RD_B(5); STG(2, pa, tn, 1);           SBAR(); MM(0); SBAR();
    RD_A(4, 1);          STG(3, pb, tn, 1);  VMC(6);  SBAR(); MM(1); SBAR();
    RD_A(6, 0); RD_B(7); STG(4, pa, tn1, 0);          SBAR(); MM(0); SBAR();
    RD_A(6, 1);          STG(5, pb, tn1, 0); VMC(6);  SBAR(); MM(1); SBAR();
  }

  const int rowb = by * 256 + wm * 128 + fq * 4;
  const bool isQ = (bx < 8);
  ushort* dst = isQ ? Qh : Kh;
  const float qscl = isQ ? 0.08838834764831845f : 1.0f;
  #pragma unroll
  for (int mf = 0; mf < 8; mf++)
    #pragma unroll
    for (int nf = 0; nf < 4; nf++){
      int col = bx * 256 + wn * 64 + nf * 16 + fr;
      int cg = col & 2047;
      int hh = cg >> 7, dd = cg & 127, jj = (cg >> 1) & 63;
      #pragma unroll
      for (int i = 0; i < 4; i++){
        int row = rowb + mf * 16 + i;
        int s = row & (S_LEN - 1), bb = row >> 11;
        float2 c2 = cs[s * 64 + jj];
        float v = acc[mf][nf][i];
        float p = __shfl_xor(v, 1);
        float o = (fr & 1) ? fmaf(p, c2.y, v * c2.x) : fmaf(v, c2.x, -p * c2.y);
        dst[((size_t)(bb * NH + hh) * S_LEN + s) * DK + dd] = f2bf(o * qscl);
      }
    }
}

// ================= 256x128 8-phase skeleton (shared by V GEMM and WO GEMM) =================
#define WSTG_A(si, tks, khh) do{ \
  const ushort* _s = pa + (tks)*64 + (khh)*32; \
  gload16(_s,                  lds + (si)*8192 + wid*512); \
  gload16(_s + (size_t)128*GK, lds + (si)*8192 + 4096 + wid*512); \
}while(0)
#define WSTG_B(si, tks, khh) do{ \
  const ushort* _s = pb + (tks)*64 + (khh)*32; \
  gload16(_s, lds + 32768 + (si)*4096 + wid*512); \
}while(0)
#define WRD_A(si, mhf) do{ \
  af[0] = *reinterpret_cast<const bf16x8*>(ldsc + (si)*16384 + wm*4096 + ((mhf)*2+0)*1024 + frA); \
  af[1] = *reinterpret_cast<const bf16x8*>(ldsc + (si)*16384 + wm*4096 + ((mhf)*2+1)*1024 + frA); \
}while(0)
#define WRD_B(si) do{ \
  bfr[0] = *reinterpret_cast<const bf16x8*>(ldsc + 65536 + (si)*8192 + wn*4096 + 0*1024 + frA); \
  bfr[1] = *reinterpret_cast<const bf16x8*>(ldsc + 65536 + (si)*8192 + wn*4096 + 1*1024 + frA); \
  bfr[2] = *reinterpret_cast<const bf16x8*>(ldsc + 65536 + (si)*8192 + wn*4096 + 2*1024 + frA); \
  bfr[3] = *reinterpret_cast<const bf16x8*>(ldsc + 65536 + (si)*8192 + wn*4096 + 3*1024 + frA); \
}while(0)
#define WMM(mhf) do{ \
  __builtin_amdgcn_s_setprio(1); \
  _Pragma("unroll") \
  for (int k2 = 0; k2 < 2; k2++) \
    _Pragma("unroll") \
    for (int nf = 0; nf < 4; nf++) \
      acc[(mhf)*2+k2][nf] = __builtin_amdgcn_mfma_f32_16x16x32_bf16(af[k2], bfr[nf], acc[(mhf)*2+k2][nf], 0, 0, 0); \
  __builtin_amdgcn_s_setprio(0); \
}while(0)

#define WBODY() \
  WSTG_A(0, 0, 0); WSTG_B(0, 0, 0); WSTG_A(1, 0, 1); WSTG_B(1, 0, 1); \
  WSTG_A(2, 1, 0); WSTG_B(2, 1, 0); \
  VMC(6); \
  SBAR(); \
  _Pragma("unroll 1") \
  for (int it = 0; it < 16; ++it){ \
    const int tb  = 2 * it + 1; \
    const int tn  = (2 * it + 2 < 32) ? 2 * it + 2 : 31; \
    const int tn1 = (2 * it + 3 < 32) ? 2 * it + 3 : 31; \
    WRD_A(0, 0); WRD_B(0); WSTG_A(3, tb, 1);            SBAR(); WMM(0); SBAR(); \
    WRD_A(0, 1);           WSTG_B(3, tb, 1);  VMC(6);   SBAR(); WMM(1); SBAR(); \
    WRD_A(1, 0); WRD_B(1); WSTG_A(0, tn, 0);            SBAR(); WMM(0); SBAR(); \
    WRD_A(1, 1);           WSTG_B(0, tn, 0);  VMC(6);   SBAR(); WMM(1); SBAR(); \
    WRD_A(2, 0); WRD_B(2); WSTG_A(1, tn, 1);            SBAR(); WMM(0); SBAR(); \
    WRD_A(2, 1);           WSTG_B(1, tn, 1);  VMC(6);   SBAR(); WMM(1); SBAR(); \
    WRD_A(3, 0); WRD_B(3); WSTG_A(2, tn1, 0);           SBAR(); WMM(0); SBAR(); \
    WRD_A(3, 1);           WSTG_B(2, tn1, 0); VMC(6);   SBAR(); WMM(1); SBAR(); \
  }

__launch_bounds__(512, 2)
__global__ void k_gemm_v(const ushort* __restrict__ A, const ushort* __restrict__ Bt,
                         ushort* __restrict__ Vt){
  __shared__ short lds[49152];   // 96 KiB
  const int tid = threadIdx.x, lane = tid & 63, wid = tid >> 6;
  const int wm = wid >> 1, wn = wid & 1;
  const int fr = lane & 15, fq = lane >> 4;

  const int bid = blockIdx.x;
  const int b2 = (bid & 7) * 32 + (bid >> 3);
  const int by = b2 >> 4, bx = b2 & 15;

  const int rbase = wid * 16 + (lane >> 2);
  const int kup = ((lane & 3) ^ ((lane >> 3) & 3)) * 8;
  const ushort* pa = A  + (size_t)(by * 256 + rbase) * GK + kup;
  const ushort* pb = Bt + (size_t)(bx * 128 + rbase) * GK + kup;

  const char* ldsc = (const char*)lds;
  const int frA = fr * 64 + ((fq * 16) ^ (((fr >> 1) & 3) << 4));

  f32x4 acc[4][4] = {};
  bf16x8 af[2], bfr[4];

  WBODY();

  const int rowb = by * 256 + wm * 64 + fq * 4;
  #pragma unroll
  for (int mf = 0; mf < 4; mf++){
    int row0 = rowb + mf * 16;
    int s0 = row0 & (S_LEN - 1), bb = row0 >> 11;
    #pragma unroll
    for (int nf = 0; nf < 4; nf++){
      int col = bx * 128 + wn * 64 + nf * 16 + fr;
      int hh = col >> 7, dd = col & 127;
      ushort4 o;
      o.x = f2bf(acc[mf][nf][0]); o.y = f2bf(acc[mf][nf][1]);
      o.z = f2bf(acc[mf][nf][2]); o.w = f2bf(acc[mf][nf][3]);
      *reinterpret_cast<ushort4*>(&Vt[((size_t)(bb * NH + hh) * DK + dd) * S_LEN + s0]) = o;
    }
  }
}

__launch_bounds__(512, 2)
__global__ void k_gemm_wo(const ushort* __restrict__ A, const ushort* __restrict__ Bt,
                          float* __restrict__ C){
  __shared__ short lds[49152];   // 96 KiB
  const int tid = threadIdx.x, lane = tid & 63, wid = tid >> 6;
  const int wm = wid >> 1, wn = wid & 1;
  const int fr = lane & 15, fq = lane >> 4;

  const int bid = blockIdx.x;
  const int b2 = (bid & 7) * 32 + (bid >> 3);
  const int by = b2 >> 4, bx = b2 & 15;

  const int rbase = wid * 16 + (lane >> 2);
  const int kup = ((lane & 3) ^ ((lane >> 3) & 3)) * 8;
  const ushort* pa = A  + (size_t)(by * 256 + rbase) * GK + kup;
  const ushort* pb = Bt + (size_t)(bx * 128 + rbase) * GK + kup;

  const char* ldsc = (const char*)lds;
  const int frA = fr * 64 + ((fq * 16) ^ (((fr >> 1) & 3) << 4));

  f32x4 acc[4][4] = {};
  bf16x8 af[2], bfr[4];

  WBODY();

  const int orow = by * 256 + wm * 64 + fq * 4;
  const int ocol = bx * 128 + wn * 64 + fr;
  #pragma unroll
  for (int mf = 0; mf < 4; mf++)
    #pragma unroll
    for (int nf = 0; nf < 4; nf++)
      #pragma unroll
      for (int i = 0; i < 4; i++)
        C[(size_t)(orow + mf * 16 + i) * DM + ocol + nf * 16] = acc[mf][nf][i];
}

// ---------------- causal flash attention: 4 waves x 16 q-rows, 64-row paired chunks ----------------
// r17 (best verified): swapped QK^T, K+V double-buffered LDS via global_load_lds, paired
// chunks (j=31-pid then pid; 33 tiles uniform), 2 blocks/CU = 8 waves/CU, defer-max,
// prescaled Q, native bf16 casts, P via per-wave 160B-stride LDS.
__launch_bounds__(256, 2)
__global__ void k_attn(const ushort* __restrict__ Q, const ushort* __restrict__ K,
                       const ushort* __restrict__ Vt, ushort* __restrict__ O){
  __shared__ short Kt[2][64 * 128];   // [kv][d] swizzled (16KB each)
  __shared__ short Vl[2][128 * 64];   // [d][kv] swizzled (16KB each)
  __shared__ short Pl[4][16 * 80];    // per-wave P, 160B row stride (2.5KB each)
  const int tid = threadIdx.x, lane = tid & 63, wid = tid >> 6;
  const int bid = blockIdx.x;
  const int pid = bid >> 5;           // 0..15
  const int bh = bid & 31;
  const int b = bh >> 4, h = bh & 15;
  const int fr = lane & 15, fq = lane >> 4;
  const int kswz = (fr & 6) << 5;     // K chunk key (row&6)<<1, byte units
  const int vswz = (fr & 7) << 4;     // V key (2-way verified)

  const ushort* kb = K  + (size_t)bh * S_LEN * DK;
  const ushort* vb = Vt + (size_t)bh * DK * S_LEN;
  char* PlB = (char*)Pl + wid * 2560;
  ushort* ob = O + (size_t)b * S_LEN * DM;

  // staging: 4 waves x 4 instrs for K and V (16KB tile each)
  int kro[4], kco[4], vro[4], vco[4];
  #pragma unroll
  for (int jj = 0; jj < 4; jj++){
    int ins = wid * 4 + jj;
    kro[jj] = ins * 4 + (lane >> 4);
    kco[jj] = 8 * ((lane & 15) ^ ((kro[jj] & 6) << 1));
    vro[jj] = ins * 8 + (lane >> 3);
    vco[jj] = 8 * ((lane & 7) ^ (vro[jj] & 7));
  }

  #pragma unroll 1
  for (int half = 0; half < 2; half++){
    const int j = half ? pid : 31 - pid;      // 64-row chunk index, 0..31
    const int qr = j * 64 + wid * 16;
    const int nt = j + 1;                     // kv tiles of 64

    bf16x8 qf[4];
    #pragma unroll
    for (int c = 0; c < 4; c++)
      qf[c] = *reinterpret_cast<const bf16x8*>(
          Q + ((size_t)bh * S_LEN + qr + fr) * DK + c * 32 + fq * 8);

    float mi = -1e30f, li = 0.f;     // per-lane scalars: q-row = qr + fr
    f32x4 accO[8] = {};

    __syncthreads();                  // protect buffers from previous half's readers
    {
      char* kd = (char*)Kt;
      char* vd = (char*)Vl;
      #pragma unroll
      for (int jj = 0; jj < 4; jj++){
        int ins = wid * 4 + jj;
        gload16(kb + (size_t)kro[jj] * DK + kco[jj],      kd + ins * 1024);
        gload16(vb + (size_t)vro[jj] * S_LEN + vco[jj],   vd + ins * 1024);
      }
    }
    __syncthreads();

    #pragma unroll 1
    for (int kt = 0; kt < nt; kt++){
      const int k0 = kt * 64;
      const int cur = kt & 1;
      if (kt + 1 < nt){
        const int k1 = k0 + 64;
        char* kd = (char*)Kt + (cur ^ 1) * 16384;
        char* vd = (char*)Vl + (cur ^ 1) * 16384;
        #pragma unroll
        for (int jj = 0; jj < 4; jj++){
          int ins = wid * 4 + jj;
          gload16(kb + (size_t)(k1 + kro[jj]) * DK + kco[jj],  kd + ins * 1024);
          gload16(vb + (size_t)vro[jj] * S_LEN + k1 + vco[jj], vd + ins * 1024);
        }
      }
      const char* KtB = (const char*)Kt + cur * 16384;
      const char* VlB = (const char*)Vl + cur * 16384;

      // ---- swapped QK^T (Q pre-scaled): lane owns q=fr, kv=16ch+4fq+i ----
      f32x4 sc[4] = {};
      #pragma unroll
      for (int c = 0; c < 4; c++){
        bf16x8 kf[4];
        #pragma unroll
        for (int ch = 0; ch < 4; ch++)
          kf[ch] = *reinterpret_cast<const bf16x8*>(
              KtB + (ch * 16 + fr) * 256 + ((c * 64 + fq * 16) ^ kswz));
        #pragma unroll
        for (int ch = 0; ch < 4; ch++)
          sc[ch] = __builtin_amdgcn_mfma_f32_16x16x32_bf16(kf[ch], qf[c], sc[ch], 0, 0, 0);
      }

      // ---- causal mask on last tile (kv = k0+16ch+4fq+i vs q = qr+fr) ----
      const int qrow = qr + fr;
      if (kt == nt - 1){
        #pragma unroll
        for (int ch = 0; ch < 4; ch++)
          #pragma unroll
          for (int i = 0; i < 4; i++)
            if (k0 + ch * 16 + fq * 4 + i > qrow) sc[ch][i] = -1e30f;
      }

      // ---- in-register row max + 2 shfl ----
      float mx = sc[0][0];
      #pragma unroll
      for (int ch = 0; ch < 4; ch++)
        #pragma unroll
        for (int i = 0; i < 4; i++) mx = fmaxf(mx, sc[ch][i]);
      mx = fmaxf(mx, __shfl_xor(mx, 16));
      mx = fmaxf(mx, __shfl_xor(mx, 32));

      // ---- T13 defer-max ----
      if (!__all(mx <= mi + 8.0f)){
        float mn = fmaxf(mi, mx);
        float scl = __expf(mi - mn);
        mi = mn;
        li *= scl;
        float sclq[4];
        #pragma unroll
        for (int i = 0; i < 4; i++) sclq[i] = __shfl(scl, fq * 4 + i);
        #pragma unroll
        for (int dt = 0; dt < 8; dt++)
          #pragma unroll
          for (int i = 0; i < 4; i++) accO[dt][i] *= sclq[i];
      }

      float rs = 0.f;
      #pragma unroll
      for (int ch = 0; ch < 4; ch++)
        #pragma unroll
        for (int i = 0; i < 4; i++){
          float e = __expf(sc[ch][i] - mi);
          sc[ch][i] = e;
          rs += e;
        }
      rs += __shfl_xor(rs, 16);
      rs += __shfl_xor(rs, 32);
      li += rs;

      // ---- P -> LDS: native casts (cvt_pk) packed to one b64 per ch ----
      #pragma unroll
      for (int ch = 0; ch < 4; ch++){
        bf16x4 pk;
        pk[0] = (__bf16)sc[ch][0]; pk[1] = (__bf16)sc[ch][1];
        pk[2] = (__bf16)sc[ch][2]; pk[3] = (__bf16)sc[ch][3];
        *reinterpret_cast<bf16x4*>(PlB + fr * 160 + ch * 32 + fq * 8) = pk;
      }
      bf16x8 pf[2];
      #pragma unroll
      for (int c2 = 0; c2 < 2; c2++)
        pf[c2] = *reinterpret_cast<const bf16x8*>(PlB + fr * 160 + c2 * 64 + fq * 16);

      // ---- PV ----
      #pragma unroll
      for (int dt = 0; dt < 8; dt++)
        #pragma unroll
        for (int c2 = 0; c2 < 2; c2++){
          bf16x8 vf = *reinterpret_cast<const bf16x8*>(
              VlB + (dt * 16 + fr) * 128 + ((c2 * 64 + fq * 16) ^ vswz));
          accO[dt] = __builtin_amdgcn_mfma_f32_16x16x32_bf16(pf[c2], vf, accO[dt], 0, 0, 0);
        }
      __syncthreads();
    }

    // ---- epilogue: inv in accO layout ----
    float inv[4];
    #pragma unroll
    for (int i = 0; i < 4; i++) inv[i] = 1.f / __shfl(li, fq * 4 + i);
    #pragma unroll
    for (int dt = 0; dt < 8; dt++)
      #pragma unroll
      for (int i = 0; i < 4; i++){
        int row = qr + fq * 4 + i;
        ob[(size_t)row * DM + h * DK + dt * 16 + fr] = f2bf(accO[dt][i] * inv[i]);
      }
  }
}

extern "C" void kernel_launch(void* const* d_in, const int* in_sizes, int n_in,
                              void* d_out, int out_size, void* d_ws, size_t ws_size,
                              hipStream_t stream){
  const float* x  = (const float*)d_in[0];
  const float* wq = (const float*)d_in[1];
  const float* wk = (const float*)d_in[2];
  const float* wv = (const float*)d_in[3];
  const float* wo = (const float*)d_in[4];
  const int* pos  = (const int*)d_in[5];
  float* out = (float*)d_out;

  char* ws = (char*)d_ws;
  ushort* xb   = (ushort*)(ws);               // 16 MiB; Ob aliases after GEMMs consume xb
  ushort* Ob   = xb;
  ushort* wqkv = (ushort*)(ws + 16777216);    // 24 MiB
  ushort* Qh   = (ushort*)(ws + 41943040);    // 16 MiB
  ushort* Kh   = (ushort*)(ws + 58720256);    // 16 MiB
  ushort* Vt   = (ushort*)(ws + 75497472);    // 16 MiB
  float2* cs   = (float2*)(ws + 92274688);    // 1 MiB
  ushort* wob  = (ushort*)(ws + 93323264);    // 8 MiB

  k_conv<<<24576 + 512, 256, 0, stream>>>(x, wq, wk, wv, wo, xb, wqkv, wob, pos, cs);

  k_gemm_qk<<<256, 512, 0, stream>>>(xb, wqkv, cs, Qh, Kh);
  k_gemm_v<<<256, 512, 0, stream>>>(xb, wqkv + (size_t)2 * DM * DM, Vt);

  k_attn<<<512, 256, 0, stream>>>(Qh, Kh, Vt, Ob);

  k_gemm_wo<<<256, 512, 0, stream>>>(Ob, wob, out);
}